// Round 12
// baseline (161.143 us; speedup 1.0000x reference)
//
#include <hip/hip_runtime.h>
#include <hip/hip_bf16.h>

// B=64, S=512, E=256, D=512
#define EDIM 256
#define SDIM 512
#define BDIM 64
#define DDIM 512
#define SPAD 514   // padded S rows per batch in Xp (2 zero rows at front)

// ws byte offsets
#define OFF_XP    0u           // bf16 [64][514][256]  = 16,842,752 B
#define OFF_BFI   16842752u    // bf16 frag-major interior weights = 1,572,864 B
#define OFF_BFT   18415616u    // bf16 frag-major tail (W1) weights = 262,144 B
#define OFF_CORR  18677760u    // f32  [512][128]  (layout [d][b*2+s])
#define OFF_BI    18939904u    // f32  [512]

// prep grid partition
#define CVT_BLOCKS  4112       // 64*514*32 / 256
#define WB_BASE     4112       // + 512 weight blocks (one per d)
#define CORR_BASE   4624       // + 4096 corr blocks (512 d x 8 b-chunks)
#define PREP_BLOCKS 8720

typedef __attribute__((ext_vector_type(8))) __bf16 bf16x8;
typedef __attribute__((ext_vector_type(4))) float  f32x4;
typedef __attribute__((ext_vector_type(8))) unsigned short ushort8v;

__device__ __forceinline__ unsigned short f2bf(float f) {
    unsigned int u = __float_as_uint(f);
    u = (u + 0x7fffu + ((u >> 16) & 1u)) >> 16;   // RNE
    return (unsigned short)u;
}

// ============ launch 1: cvt_pad + weight-fragment + edge-correction ============
__global__ __launch_bounds__(256) void prep_all(
    const float* __restrict__ X,
    const float* __restrict__ W1, const float* __restrict__ b1,
    const float* __restrict__ W2, const float* __restrict__ b2,
    const float* __restrict__ W3, const float* __restrict__ b3,
    const float* __restrict__ W4, const float* __restrict__ b4,
    char* __restrict__ wsb)
{
    const int tid = threadIdx.x;

    if (blockIdx.x < CVT_BLOCKS) {
        unsigned short* Xp = (unsigned short*)(wsb + OFF_XP);
        const int i   = blockIdx.x * 256 + tid;    // [0, 64*514*32)
        const int row = i >> 5;                    // b*514 + j
        const int q   = i & 31;                    // 8-elem group
        const int b   = row / SPAD;
        const int j   = row - b * SPAD;
        ushort8v v;
        if (j < 2) {
            v = (ushort8v)0;
        } else {
            const float* src = X + ((size_t)(b * SDIM + j - 2)) * EDIM + q * 8;
            const float4 f0 = *(const float4*)(src);
            const float4 f1 = *(const float4*)(src + 4);
            v[0] = f2bf(f0.x); v[1] = f2bf(f0.y); v[2] = f2bf(f0.z); v[3] = f2bf(f0.w);
            v[4] = f2bf(f1.x); v[5] = f2bf(f1.y); v[6] = f2bf(f1.z); v[7] = f2bf(f1.w);
        }
        *(ushort8v*)(Xp + (size_t)row * EDIM + q * 8) = v;
        return;
    }

    if (blockIdx.x < CORR_BASE) {
        // ---- combined weights -> fragment-major, one block per d (coalesced reads) ----
        const int d = blockIdx.x - WB_BASE;  // 0..511
        const int e = tid;                   // 0..255
        const int de = d * EDIM + e;

        const float w1  = W1[de];
        const float w20 = W2[de * 2 + 0], w21 = W2[de * 2 + 1];
        const float w30 = W3[de * 3 + 0], w31 = W3[de * 3 + 1], w32 = W3[de * 3 + 2];
        const float w40 = W4[de * 4 + 0], w41 = W4[de * 4 + 1], w42 = W4[de * 4 + 2], w43 = W4[de * 4 + 3];

        float g[6];
        g[0] = w40;
        g[1] = w30 + w40 + w41;
        g[2] = w1 + w20 + w30 + w31 + w40 + w41 + w42;
        g[3] = w21 + w31 + w32 + w41 + w42 + w43;
        g[4] = w32 + w42 + w43;
        g[5] = w43;

        const int fm = d & 15, t = (d >> 4) & 3, h = (d >> 6) & 1, c = d >> 7;
        const int hi = (e >> 3) & 3, j = e & 7, eb = e >> 5;
        char* ibase = wsb + OFF_BFI + (size_t)((c * 2 + h) * 48) * 4096
                    + t * 1024 + hi * 256 + fm * 16 + j * 2;
#pragma unroll
        for (int s = 0; s < 6; ++s)
            *(unsigned short*)(ibase + (size_t)(s * 8 + eb) * 4096) = f2bf(g[s]);

        *(unsigned short*)(wsb + OFF_BFT + (size_t)((c * 2 + h) * 8 + eb) * 4096
                           + t * 1024 + hi * 256 + fm * 16 + j * 2) = f2bf(w1);

        if (e == 0)
            ((float*)(wsb + OFF_BI))[d] = b1[d] + b2[d] + 2.0f * b3[d] + 3.0f * b4[d];
        return;
    }

    // ---- edge correction, block = (d, 8-batch chunk); coalesced weight rows.
    {
        __shared__ float cls[16];
        const int cb = blockIdx.x - CORR_BASE;   // 0..4095
        const int d  = cb >> 3;                  // 0..511
        const int bq = (cb & 7) * 8;             // batch chunk base
        const int e  = tid;                      // 0..255

        if (tid < 16) cls[tid] = 0.f;

        const float w31 = W3[(size_t)d * 768 + 3 * e + 1];
        const float w32 = W3[(size_t)d * 768 + 3 * e + 2];
        const float4 w4v = *(const float4*)(W4 + (size_t)d * 1024 + 4 * e);
        const float w41 = w4v.y, w42 = w4v.z, w43 = w4v.w;

        const float c00 = w31 + w41 + w42;
        const float c01 = w32 + w42 + w43;
        const float c02 = w43;
        __syncthreads();

#pragma unroll
        for (int bi = 0; bi < 8; ++bi) {
            const float* xr = X + (size_t)(bq + bi) * (SDIM * EDIM) + e;
            const float x0 = xr[0], x1 = xr[EDIM], x2 = xr[2 * EDIM];
            float a0 = c00 * x0 + c01 * x1 + c02 * x2;
            float a1 = w41 * x0 + w42 * x1 + w43 * x2;
#pragma unroll
            for (int off = 32; off >= 1; off >>= 1) {
                a0 += __shfl_xor(a0, off, 64);
                a1 += __shfl_xor(a1, off, 64);
            }
            if ((tid & 63) == 0) {
                atomicAdd(&cls[bi * 2 + 0], a0);
                atomicAdd(&cls[bi * 2 + 1], a1);
            }
        }
        __syncthreads();

        if (tid < 16) {
            const int s = tid & 1;
            const float bc = s ? b4[d] : (b3[d] + 2.f * b4[d]);
            ((float*)(wsb + OFF_CORR))[(size_t)d * 128 + bq * 2 + tid] = -cls[tid] - bc;
        }
    }
}

// ============ launch 2: K=64-phase GEMM + LDS-transpose NT epilogue (R10) ============
// GEMM core verbatim from R9 (passed). R10 changes ONLY the epilogue:
// R0-R9 wrote 16.8M scalar dword stores (4 disjoint 64B half-lines per wave
// store, j=0/j=1 partial-line pairs; ~5MB RMW-fetch signature) — the one
// component never varied while dur_us sat pinned at ~46us. Now: acc (+bias,
// +corr) -> LDS tile [128][132 f32] (stride 132 -> 16B-aligned rows; b32
// writes <=4-way, b128 reads 2-way=free) -> barrier -> each wave reads rows
// back as f32x4 and issues NONTEMPORAL dwordx4 stores: 2 rows x 512B fully
// contiguous per wave-store, full 128B lines, 4x fewer store instrs, no L2
// pollution from the never-re-read 67MB output.
#define GLL(src, dst) \
    __builtin_amdgcn_global_load_lds((const __attribute__((address_space(1))) void*)(src), \
                                     (__attribute__((address_space(3))) void*)(dst), 16, 0, 0)

#define TSTRIDE 132   // f32 stride of transpose tile rows (528 B, 16B-aligned)

__global__ __launch_bounds__(512, 4) void mega(
    const unsigned short* __restrict__ Xp,
    const char* __restrict__ wsb,
    const float* __restrict__ b1,
    float* __restrict__ out)
{
    __shared__ __align__(16) char smem[67584];   // max(4x16KB A-buffers, 128x132 f32 tile)
    const int id  = blockIdx.x;                  // natural: XCD = id%8 = strip%8
    const int strip = id & 127;                  // 128 strips x 128 rows
    const int c     = id >> 7;                   // col block 0..3
    const int col0  = c * 128;
    const int tid = threadIdx.x;
    const int w = tid >> 6, l = tid & 63;

    // A staging: wave w stages rows [16w,16w+16): 2 GLL x 8 rows x 128B
    const int swz = ((l & 7) ^ (l >> 3)) * 16;   // pre-swizzled source slot (8 slots)
    const int r0  = strip * 128 + 16 * w + (l >> 3);
    const int r1  = r0 + 8;
    const int ba0 = r0 >> 8, sa0 = r0 & 255;
    const int ba1 = r1 >> 8, sa1 = r1 & 255;

    const int oA0 = (16 * w) * 128;              // wave-uniform LDS stage offsets
    const int oA1 = oA0 + 1024;
    char* q0 = smem;
    char* q1 = smem + 16384;
    char* q2 = smem + 32768;
    char* q3 = smem + 49152;

    const int wrg = (w >> 2) * 64;               // wave row-group (0 or 64)
    const int qc  = w & 3;                       // wave col-quarter (32 cols)
    const int fm  = l & 15;
    const int hi4 = l >> 4;
    // read slots (bytes) for k-step 0 / 1 within the 64-K phase
    const int rs0 = ((hi4)     ^ (fm & 7)) * 16;
    const int rs1 = ((4 + hi4) ^ (fm & 7)) * 16;

    // B frag pointers: half hq = qc>>1, frag t = (qc&1)*2 + j  (cols qc*32 + j*16)
    const int hq   = qc >> 1;
    const int toff = (qc & 1) * 2048;
    const char* bfi = wsb + OFF_BFI + (size_t)(c * 2 + hq) * (48 * 4096) + toff + l * 16;
    const char* bft = wsb + OFF_BFT + (size_t)(c * 2 + hq) * (8 * 4096)  + toff + l * 16;

    f32x4 acc[4][2];
    const char *ga0, *ga1;

    auto LOADB = [&](bf16x8 (&dst)[4], const char* base, int ph) {
#pragma unroll
        for (int ks = 0; ks < 2; ++ks)
#pragma unroll
            for (int j = 0; j < 2; ++j)
                dst[ks * 2 + j] = *(const bf16x8*)(base + (size_t)(2 * ph + ks) * 4096 + j * 1024);
    };
    auto STAGE = [&](char* buf) {
        GLL(ga0, buf + oA0);
        GLL(ga1, buf + oA1);
        ga0 += 128; ga1 += 128;
    };
    auto COMP = [&](const char* buf, const bf16x8 (&b)[4]) {
#pragma unroll
        for (int ks = 0; ks < 2; ++ks) {
            bf16x8 af[4];
            const int rs = ks ? rs1 : rs0;
#pragma unroll
            for (int t = 0; t < 4; ++t)
                af[t] = *(const bf16x8*)(buf + (wrg + t * 16 + fm) * 128 + rs);
#pragma unroll
            for (int i = 0; i < 4; ++i)
#pragma unroll
                for (int j = 0; j < 2; ++j)
                    acc[i][j] = __builtin_amdgcn_mfma_f32_16x16x32_bf16(af[i], b[ks * 2 + j], acc[i][j], 0, 0, 0);
        }
    };

#define PH6  asm volatile("s_waitcnt vmcnt(6) lgkmcnt(0)" ::: "memory"); \
             __builtin_amdgcn_s_barrier();
#define PH0  asm volatile("s_waitcnt vmcnt(0) lgkmcnt(0)" ::: "memory"); \
             __builtin_amdgcn_s_barrier();
#define DO_COMP(Q, B) __builtin_amdgcn_s_setprio(1); COMP(Q, B); __builtin_amdgcn_s_setprio(0);

    auto GEMM = [&](const char* bbase, int np) {   // np % 4 == 0, np >= 4
        bf16x8 b0[4], b1r[4], b2[4], b3[4];
        STAGE(q0); LOADB(b0,  bbase, 0);
        STAGE(q1); LOADB(b1r, bbase, 1);           // 12 ops outstanding
#pragma unroll 1
        for (int p = 0; p + 4 < np; p += 4) {
            PH6; STAGE(q2); LOADB(b2,  bbase, p + 2); DO_COMP(q0, b0);
            PH6; STAGE(q3); LOADB(b3,  bbase, p + 3); DO_COMP(q1, b1r);
            PH6; STAGE(q0); LOADB(b0,  bbase, p + 4); DO_COMP(q2, b2);
            PH6; STAGE(q1); LOADB(b1r, bbase, p + 5); DO_COMP(q3, b3);
        }
        // final 4 phases: stage only np-2, np-1
        PH6; STAGE(q2); LOADB(b2, bbase, np - 2); DO_COMP(q0, b0);
        PH6; STAGE(q3); LOADB(b3, bbase, np - 1); DO_COMP(q1, b1r);
        PH6;                                      DO_COMP(q2, b2);
        PH0;                                      DO_COMP(q3, b3);
    };

    // ---- R10 epilogue: acc -> LDS transpose tile -> f32x4 NT stores ----
    // entry condition: PH0 already executed (all waves' GEMM ds_reads drained)
    // exit: LDS reads drained + barrier -> buffers safe to re-stage
    auto EPI = [&](int s_base, bool with_corr) {
        const float* bias = with_corr ? (const float*)(wsb + OFF_BI) : b1;
        const float* corr = (const float*)(wsb + OFF_CORR);   // [d][b*2+s]
        const int ocol = col0 + qc * 32 + fm;
        const int rq   = hi4 * 4;
        float bv[2];
#pragma unroll
        for (int j = 0; j < 2; ++j) bv[j] = bias[ocol + j * 16];

        float* T = (float*)smem;
        // phase 1: deposit acc(+bias,+corr) at [row][col], stride TSTRIDE
#pragma unroll
        for (int i = 0; i < 4; ++i) {
#pragma unroll
            for (int r = 0; r < 4; ++r) {
                const int row = wrg + i * 16 + rq + r;        // 0..127
                const int rr  = strip * 128 + row;
                const int ssl = rr & 255;
                const int bb  = rr >> 8;
#pragma unroll
                for (int j = 0; j < 2; ++j) {
                    float v = acc[i][j][r] + bv[j];
                    if (with_corr && ssl < 2)
                        v += corr[(size_t)(ocol + j * 16) * 128 + bb * 2 + ssl];
                    T[row * TSTRIDE + qc * 32 + j * 16 + fm] = v;
                }
            }
        }
        asm volatile("s_waitcnt lgkmcnt(0)" ::: "memory");
        __builtin_amdgcn_s_barrier();
        // phase 2: rows back out as contiguous f32x4 NT stores
        const int c16   = l & 31;              // 16B chunk within 512B row-slice
        const int rhalf = l >> 5;
#pragma unroll
        for (int itr = 0; itr < 8; ++itr) {
            const int row = w * 16 + 2 * itr + rhalf;
            const f32x4 v = *(const f32x4*)(T + row * TSTRIDE + c16 * 4);
            const int rr  = strip * 128 + row;
            const int ssl = rr & 255;
            const int bb  = rr >> 8;
            float* op = out + ((size_t)(bb * SDIM + s_base + ssl)) * DDIM + col0 + c16 * 4;
            __builtin_nontemporal_store(v, (f32x4*)op);
        }
        asm volatile("s_waitcnt lgkmcnt(0)" ::: "memory");
        __builtin_amdgcn_s_barrier();          // LDS safe for next GEMM staging
    };

    // ---- interior: A row r=(b,s) is Xp[b][s : s+6][:] flattened (im2col), 24 phases ----
#pragma unroll
    for (int i = 0; i < 4; ++i)
#pragma unroll
        for (int j = 0; j < 2; ++j) acc[i][j] = (f32x4){0.f, 0.f, 0.f, 0.f};
    ga0 = (const char*)(Xp + (size_t)(ba0 * SPAD + sa0) * EDIM) + swz;
    ga1 = (const char*)(Xp + (size_t)(ba1 * SPAD + sa1) * EDIM) + swz;
    GEMM(bfi, 24);
    EPI(0, true);

    // ---- tail: s in [256,512), unigram only: A row = Xp[b][s+2][:], 4 phases ----
#pragma unroll
    for (int i = 0; i < 4; ++i)
#pragma unroll
        for (int j = 0; j < 2; ++j) acc[i][j] = (f32x4){0.f, 0.f, 0.f, 0.f};
    ga0 = (const char*)(Xp + (size_t)(ba0 * SPAD + 258 + sa0) * EDIM) + swz;
    ga1 = (const char*)(Xp + (size_t)(ba1 * SPAD + 258 + sa1) * EDIM) + swz;
    GEMM(bft, 4);
    EPI(256, false);
}

extern "C" void kernel_launch(void* const* d_in, const int* in_sizes, int n_in,
                              void* d_out, int out_size, void* d_ws, size_t ws_size,
                              hipStream_t stream)
{
    const float* X  = (const float*)d_in[0];
    const float* W1 = (const float*)d_in[1];
    const float* b1 = (const float*)d_in[2];
    const float* W2 = (const float*)d_in[3];
    const float* b2 = (const float*)d_in[4];
    const float* W3 = (const float*)d_in[5];
    const float* b3 = (const float*)d_in[6];
    const float* W4 = (const float*)d_in[7];
    const float* b4 = (const float*)d_in[8];
    float* out = (float*)d_out;
    char*  wsb = (char*)d_ws;

    prep_all<<<dim3(PREP_BLOCKS), dim3(256), 0, stream>>>(X, W1, b1, W2, b2, W3, b3, W4, b4, wsb);

    mega<<<dim3(512), dim3(512), 0, stream>>>(
        (const unsigned short*)(wsb + OFF_XP), wsb, b1, out);
}